// Round 9
// baseline (232.942 us; speedup 1.0000x reference)
//
#include <hip/hip_runtime.h>

#define NEG (-10000.0f)
#define START_TAG 62
#define STOP_TAG 63
#define SLEN 512
#define BATCH 512
#define NTAG 64

__device__ __forceinline__ float readlane_f(float v, int lane) {
    return __uint_as_float(__builtin_amdgcn_readlane(__float_as_uint(v), lane));
}

// One wave per batch; lane j = tag j.
//
// Round-13: LDS-broadcast structure (R3/R7: 590 cyc/step) resisted two manual
// scheduling attempts -- its 16 uniform ds_read_b128 (~190 cyc DS occupancy +
// ~120 cyc return) are structurally on the chain. Replace with REGISTER-ONLY
// broadcast: q' stays in VGPRs; 64 v_readlane -> SGPR + 64 v_fma(SGPR,VGPR)
// software-pipelined at distance 8 (R0 measured the readlane->fma hazard at
// ~9 cyc ONLY when adjacent; >=8-inst separation hides it). 4 accumulator
// chains; e as 64 scalar VGPRs. DS ops/step: 18 -> 1 (mask). Expected chain
// ~330-400 cyc/step vs 590.
//
// Exp-space recursion (verified rounds 7-12):
//   acc_j = sum_i q_i * E_ij
//   q'_j  = acc_j * exp(f_j) * rinv,  rinv = 2^-k exact from prior acc[lane0]
//   logz  = log(sum_j q_j e^tstop_j) + C0 + ktot*ln2
__global__ __launch_bounds__(64) __attribute__((amdgpu_waves_per_eu(1, 1)))
void crf_fwd(const float* __restrict__ feats,
             const int* __restrict__ tags,
             const float* __restrict__ mask,
             const float* __restrict__ trans,
             float* __restrict__ diff /* [BATCH] */) {
    const int b = blockIdx.x;
    const int j = threadIdx.x; // tag lane 0..63

    __shared__ float smask[SLEN]; // wave-uniform mask column

    // ---- E column in registers: e[i] = exp(trans[i][j]) (64 scalar VGPRs) --
    float e[NTAG];
    float colsum = 0.0f;
#pragma unroll
    for (int i = 0; i < NTAG; ++i) {
        e[i] = __expf(trans[i * NTAG + j]); // exp(NEG) -> 0, desired
        colsum += e[i];
    }
    const float tstop = trans[STOP_TAG * NTAG + j];

    // ---- mask column preload (regs reused by epilogue 2) ----
    float mreg[8];
#pragma unroll
    for (int k = 0; k < 8; ++k) mreg[k] = mask[(64 * k + j) * BATCH + b];
#pragma unroll
    for (int k = 0; k < 8; ++k) smask[64 * k + j] = mreg[k];

    // ---- step 0 (exact analytic; trans[START,:]==NEG) ----
    float f_s0 = feats[(size_t)b * NTAG + j]; // feats[0][b][j]
    float m0 = readlane_f(mreg[0], 0);
    float alpha0 = (m0 > 0.0f) ? (NEG + log1pf(colsum) + f_s0)
                               : ((j == START_TAG) ? 0.0f : NEG);
    const float C0 = readlane_f(alpha0, START_TAG);
    float q = __expf(alpha0 - C0); // cold: exp(NEG)->0 except START lane = 1

    if (j == 0) smask[0] = 0.0f; // s=0 loop iteration is a masked no-op
    __syncthreads(); // single wave: cheap; orders smask init before loop reads

    // ---- feats ring prefetch depth 4 (only vmcnt loads in the loop) ----
    const float* fp = feats + (size_t)b * NTAG + j;
    float fr[4];
#pragma unroll
    for (int t = 0; t < 4; ++t) fr[t] = fp[(size_t)t * BATCH * NTAG];

    float rinv = 1.0f; // wave-uniform pending normalizer 2^-kcur
    int kcur = 0;      // exponent embedded in rinv
    int ktot = 0;      // sum of APPLIED exponents

    for (int blk = 0; blk < 128; ++blk) {
#pragma unroll
        for (int t = 0; t < 4; ++t) {
            const int s = blk * 4 + t;

            const float mk = smask[s]; // the ONLY DS op in the loop (off-chain)

            // ---- off-chain: exp(f), prefetch, scale prep ----
            float ef = __expf(fr[t]); // operand loaded 4 steps ago
            int sp = s + 4;
            if (sp > SLEN - 1) sp = SLEN - 1; // tail garbage, never consumed
            fr[t] = fp[(size_t)sp * BATCH * NTAG];
            float efr = ef * rinv; // rinv known from last step

            // ---- register broadcast: readlane pipelined at distance 8 ----
            unsigned qu = __float_as_uint(q);
            float su[64];
            float acc[4] = {0.0f, 0.0f, 0.0f, 0.0f};
#pragma unroll
            for (int i = 0; i < 8; ++i)
                su[i] = __uint_as_float(__builtin_amdgcn_readlane(qu, i));
#pragma unroll
            for (int i = 0; i < NTAG; ++i) {
                if (i < NTAG - 8)
                    su[i + 8] = __uint_as_float(
                        __builtin_amdgcn_readlane(qu, i + 8));
                acc[i & 3] = fmaf(su[i], e[i], acc[i & 3]);
            }
            float acc_s = (acc[0] + acc[1]) + (acc[2] + acc[3]);

            float qn = acc_s * efr;
            bool upd = (mk > 0.0f);
            q = upd ? qn : q; // masked step: q unchanged

            // ---- renormalizer bookkeeping (off the critical chain) ----
            ktot = upd ? (ktot + kcur) : ktot; // kcur was applied this step
            unsigned a0u = __builtin_amdgcn_readfirstlane(__float_as_uint(acc_s));
            int ke = (int)((a0u >> 23) & 0xffu) - 127; // floor exp of acc[0] (>0)
            ke = (ke < -60) ? -60 : ((ke > 60) ? 60 : ke); // runaway guard
            float rnew = __uint_as_float((unsigned)(127 - ke) << 23); // exact 2^-ke
            rinv = upd ? rnew : rinv;
            kcur = upd ? ke : kcur;
        }
    }

    // ---- epilogue 1: logz = log(sum_j q_j * exp(tstop_j)) + C0 + ktot*ln2 ----
    float et = __expf(tstop); // tstop[STOP]=NEG -> 0; q[STOP]=0 anyway
    float pe = q * et;
#pragma unroll
    for (int w = 32; w >= 1; w >>= 1) pe += __shfl_xor(pe, w, 64);
    float logz = __logf(pe) + C0 + (float)ktot * 0.6931471805599453f;

    // ---- epilogue 2: true-path score; lanes parallel over time steps ----
    float psc = 0.0f, pms = 0.0f;
#pragma unroll
    for (int k = 0; k < 8; ++k) {
        int s = j + 64 * k;
        int tg = tags[s * BATCH + b];
        float mkk = mreg[k]; // this lane's preloaded mask[s]
        int tprev = (s == 0) ? START_TAG : tags[(s - 1) * BATCH + b];
        float em = feats[((size_t)s * BATCH + b) * NTAG + tg];
        psc = fmaf(em + trans[tprev * NTAG + tg], mkk, psc);
        pms += mkk;
    }
#pragma unroll
    for (int w = 32; w >= 1; w >>= 1) {
        psc += __shfl_xor(psc, w, 64);
        pms += __shfl_xor(pms, w, 64);
    }

    if (j == 0) {
        int last_idx = (int)(pms + 0.5f) - 1;
        int ltag = tags[last_idx * BATCH + b];
        float score = psc + trans[ltag * NTAG + STOP_TAG];
        diff[b] = logz - score;
    }
}

__global__ __launch_bounds__(512) void crf_reduce(const float* __restrict__ diff,
                                                  float* __restrict__ out) {
    __shared__ float sdata[8];
    int t = threadIdx.x;
    float val = diff[t];
#pragma unroll
    for (int w = 32; w >= 1; w >>= 1)
        val += __shfl_xor(val, w, 64);
    if ((t & 63) == 0) sdata[t >> 6] = val;
    __syncthreads();
    if (t == 0) {
        float ssum = 0.0f;
        for (int i = 0; i < 8; ++i) ssum += sdata[i];
        out[0] = ssum * (1.0f / (float)BATCH);
    }
}

extern "C" void kernel_launch(void* const* d_in, const int* in_sizes, int n_in,
                              void* d_out, int out_size, void* d_ws, size_t ws_size,
                              hipStream_t stream) {
    const float* feats = (const float*)d_in[0];
    const int* tags = (const int*)d_in[1];
    const float* mask = (const float*)d_in[2];
    const float* trans = (const float*)d_in[3];
    float* out = (float*)d_out;
    float* diff = (float*)d_ws; // 512 floats

    crf_fwd<<<BATCH, 64, 0, stream>>>(feats, tags, mask, trans, diff);
    crf_reduce<<<1, 512, 0, stream>>>(diff, out);
}